// Round 1
// baseline (262.643 us; speedup 1.0000x reference)
//
#include <hip/hip_runtime.h>

typedef unsigned short u16;
typedef unsigned int u32;
typedef __attribute__((ext_vector_type(8))) short bfrag;   // 8 bf16 (4 VGPRs)
typedef __attribute__((ext_vector_type(4))) float facc;    // 4 fp32

#define N 8192
#define DIM 512
#define BM 128
#define BN 128
#define BK 64
#define NSPLIT 8
#define CPS (N / NSPLIT)          // 1024 columns per split
#define NPART (NSPLIT * 2)        // 16 partials per row (2 wc-halves per block)
#define NCLS 100

#if __has_builtin(__builtin_amdgcn_exp2f)
#define EXP2(x) __builtin_amdgcn_exp2f(x)
#else
#define EXP2(x) exp2f(x)
#endif

__device__ __forceinline__ u16 f2bf(float f) {            // RNE fp32->bf16
  u32 u = __float_as_uint(f);
  u32 r = u + 0x7fffu + ((u >> 16) & 1u);
  return (u16)(r >> 16);
}
__device__ __forceinline__ float bf2f(u16 h) {
  return __uint_as_float(((u32)h) << 16);
}

// ---- prep: scale by sqrt(log2e/0.035) and split fp32 -> bf16 hi/lo --------
// After this, Gram(Ahi+Alo) = D * log2(e), i.e. exp2() domain directly.
__global__ void prep_kernel(const float* __restrict__ F, u16* __restrict__ Ahi,
                            u16* __restrict__ Alo, float* __restrict__ classSum,
                            int* __restrict__ classCnt)
{
  const float sc = sqrtf(1.4426950408889634f / 0.035f);
  int idx = (blockIdx.x * 256 + threadIdx.x) * 4;
  float4 x = *(const float4*)(F + idx);
  float v[4] = {x.x * sc, x.y * sc, x.z * sc, x.w * sc};
  u16 h[4], l[4];
#pragma unroll
  for (int i = 0; i < 4; ++i) {
    h[i] = f2bf(v[i]);
    l[i] = f2bf(v[i] - bf2f(h[i]));
  }
  *(ushort4*)(Ahi + idx) = make_ushort4(h[0], h[1], h[2], h[3]);
  *(ushort4*)(Alo + idx) = make_ushort4(l[0], l[1], l[2], l[3]);
  if (blockIdx.x == 0 && threadIdx.x < NCLS) {   // zero class accumulators
    classSum[threadIdx.x] = 0.f;
    classCnt[threadIdx.x] = 0;
  }
}

__device__ __forceinline__ void stage16(const u16* g, u16* l) {
  __builtin_amdgcn_global_load_lds((const __attribute__((address_space(1))) void*)g,
                                   (__attribute__((address_space(3))) void*)l, 16, 0, 0);
}

// ---- main: flash-style Gram + online masked max / sum-exp2 ----------------
// Block: 4 waves (2x2), 128x128 D-tile per col-iter, K=512 in BK=64 steps.
// D ~ Ahi*Ahi^T + Ahi*Alo^T + Alo*Ahi^T (fp32 accum) -- bf16x2 split GEMM.
__global__ __launch_bounds__(256, 2) void gram_flash(
    const u16* __restrict__ Ahi, const u16* __restrict__ Alo,
    const int* __restrict__ labels,
    float* __restrict__ m_part, float* __restrict__ s_part)
{
  __shared__ __align__(16) u16 lds[4 * BM * BK];   // 64 KB: ahi, alo, bhi, blo
  u16* lds_ahi = lds;
  u16* lds_alo = lds + BM * BK;
  u16* lds_bhi = lds + 2 * BM * BK;
  u16* lds_blo = lds + 3 * BM * BK;

  const int tid = threadIdx.x;
  const int wave = tid >> 6;
  const int lane = tid & 63;
  const int wr = wave >> 1, wc = wave & 1;
  const int l15 = lane & 15, lg = lane >> 4;

  const int rb = blockIdx.x & 63;    // 64 row blocks
  const int cs = blockIdx.x >> 6;    // 8 column splits
  const int i0 = rb * BM;
  const int jbase = cs * CPS;

  // row labels for this lane's 16 rows, packed 4x8bit per mi
  u32 lr[4];
#pragma unroll
  for (int mi = 0; mi < 4; ++mi) {
    u32 pk = 0;
#pragma unroll
    for (int rg = 0; rg < 4; ++rg) {
      int r = i0 + wr * 64 + mi * 16 + lg * 4 + rg;
      pk |= ((u32)labels[r >> 1] & 0xffu) << (8 * rg);
    }
    lr[mi] = pk;
  }

  float m_run[16], s_run[16];      // running max (log2 units, floor 0) and sum
#pragma unroll
  for (int i = 0; i < 16; ++i) { m_run[i] = 0.f; s_run[i] = 0.f; }

  for (int t = 0; t < CPS / BN; ++t) {
    const int j0 = jbase + t * BN;
    int lc[4];
#pragma unroll
    for (int ni = 0; ni < 4; ++ni)
      lc[ni] = labels[(j0 + wc * 64 + ni * 16 + l15) >> 1];

    facc acc[4][4];
#pragma unroll
    for (int a = 0; a < 4; ++a)
#pragma unroll
      for (int b = 0; b < 4; ++b)
        acc[a][b] = (facc){0.f, 0.f, 0.f, 0.f};

    for (int kk = 0; kk < DIM; kk += BK) {
      __syncthreads();   // previous K-step's ds_reads done before overwrite
      // stage 4 tiles of [128][64] bf16 via global_load_lds(16B).
      // LDS dest is linear; bank-conflict swizzle is applied by permuting the
      // GLOBAL source chunk (cg = cp ^ (row&7)) -- rule 21 both-sides.
#pragma unroll
      for (int q = 0; q < 4; ++q) {
        const int ci = (wave * 4 + q) * 64 + lane;  // 16B-chunk index in tile
        const int row = ci >> 3;                    // 0..127
        const int cp = ci & 7;                      // linear dest chunk
        const int cg = cp ^ (row & 7);              // swizzled source chunk
        const size_t goffA = (size_t)(i0 + row) * DIM + kk + cg * 8;
        const size_t goffB = (size_t)(j0 + row) * DIM + kk + cg * 8;
        const int lbase = (wave * 4 + q) * 512;     // wave-uniform LDS base
        stage16(Ahi + goffA, lds_ahi + lbase);
        stage16(Alo + goffA, lds_alo + lbase);
        stage16(Ahi + goffB, lds_bhi + lbase);
        stage16(Alo + goffB, lds_blo + lbase);
      }
      asm volatile("s_waitcnt vmcnt(0)" ::: "memory");
      __syncthreads();

#pragma unroll
      for (int k2 = 0; k2 < 2; ++k2) {
        bfrag fah[4], fal[4], fbh[4], fbl[4];
#pragma unroll
        for (int mi = 0; mi < 4; ++mi) {
          const int row = wr * 64 + mi * 16 + l15;
          const int cc = (k2 * 4 + lg) ^ (row & 7); // un-swizzle on read
          const int off = row * 64 + cc * 8;
          fah[mi] = *(const bfrag*)(lds_ahi + off);
          fal[mi] = *(const bfrag*)(lds_alo + off);
        }
#pragma unroll
        for (int ni = 0; ni < 4; ++ni) {
          const int row = wc * 64 + ni * 16 + l15;
          const int cc = (k2 * 4 + lg) ^ (row & 7);
          const int off = row * 64 + cc * 8;
          fbh[ni] = *(const bfrag*)(lds_bhi + off);
          fbl[ni] = *(const bfrag*)(lds_blo + off);
        }
#pragma unroll
        for (int mi = 0; mi < 4; ++mi)
#pragma unroll
          for (int ni = 0; ni < 4; ++ni)
            acc[mi][ni] = __builtin_amdgcn_mfma_f32_16x16x32_bf16(fah[mi], fbh[ni], acc[mi][ni], 0, 0, 0);
#pragma unroll
        for (int mi = 0; mi < 4; ++mi)
#pragma unroll
          for (int ni = 0; ni < 4; ++ni)
            acc[mi][ni] = __builtin_amdgcn_mfma_f32_16x16x32_bf16(fah[mi], fbl[ni], acc[mi][ni], 0, 0, 0);
#pragma unroll
        for (int mi = 0; mi < 4; ++mi)
#pragma unroll
          for (int ni = 0; ni < 4; ++ni)
            acc[mi][ni] = __builtin_amdgcn_mfma_f32_16x16x32_bf16(fal[mi], fbh[ni], acc[mi][ni], 0, 0, 0);
      }
    }

    // online masked max / sum-exp2 update (values already in log2 domain)
#pragma unroll
    for (int mi = 0; mi < 4; ++mi) {
#pragma unroll
      for (int rg = 0; rg < 4; ++rg) {
        const int si = mi * 4 + rg;
        const int labr = (int)((lr[mi] >> (8 * rg)) & 0xffu);
        float v0 = (labr == lc[0]) ? -1e30f : acc[mi][0][rg];
        float v1 = (labr == lc[1]) ? -1e30f : acc[mi][1][rg];
        float v2 = (labr == lc[2]) ? -1e30f : acc[mi][2][rg];
        float v3 = (labr == lc[3]) ? -1e30f : acc[mi][3][rg];
        float lm = fmaxf(fmaxf(v0, v1), fmaxf(v2, v3));
        float M = fmaxf(m_run[si], lm);              // M >= 0 always
        float fac = EXP2(m_run[si] - M);
        float e0 = EXP2(v0 - M);                     // masked -> exp2(-1e30) = 0
        float e1 = EXP2(v1 - M);
        float e2 = EXP2(v2 - M);
        float e3 = EXP2(v3 - M);
        s_run[si] = s_run[si] * fac + ((e0 + e1) + (e2 + e3));
        m_run[si] = M;
      }
    }
  }

  // merge the 16 column-lanes within each row group (butterfly)
#pragma unroll
  for (int st = 1; st <= 8; st <<= 1) {
#pragma unroll
    for (int si = 0; si < 16; ++si) {
      float m2 = __shfl_xor(m_run[si], st, 64);
      float s2 = __shfl_xor(s_run[si], st, 64);
      float M = fmaxf(m_run[si], m2);
      s_run[si] = s_run[si] * EXP2(m_run[si] - M) + s2 * EXP2(m2 - M);
      m_run[si] = M;
    }
  }

  if (l15 == 0) {
    const int p = cs * 2 + wc;
#pragma unroll
    for (int mi = 0; mi < 4; ++mi)
#pragma unroll
      for (int rg = 0; rg < 4; ++rg) {
        const int r = i0 + wr * 64 + mi * 16 + lg * 4 + rg;
        m_part[p * N + r] = m_run[mi * 4 + rg];
        s_part[p * N + r] = s_run[mi * 4 + rg];
      }
  }
}

// ---- combine partials per row, accumulate per-class sums ------------------
__global__ void combine_kernel(const float* __restrict__ m_part,
                               const float* __restrict__ s_part,
                               const int* __restrict__ labels,
                               float* __restrict__ classSum,
                               int* __restrict__ classCnt)
{
  int j = blockIdx.x * 256 + threadIdx.x;
  float mv[NPART];
#pragma unroll
  for (int p = 0; p < NPART; ++p) mv[p] = m_part[p * N + j];
  float M = 0.f;
#pragma unroll
  for (int p = 0; p < NPART; ++p) M = fmaxf(M, mv[p]);
  float S = 0.f;
#pragma unroll
  for (int p = 0; p < NPART; ++p) S += s_part[p * N + j] * EXP2(mv[p] - M);
  int c = labels[j >> 1];
  atomicAdd(&classSum[c], S);
  atomicAdd(&classCnt[c], 1);
}

// ---- finalize: loss = (1/N) * sum_c cnt_c * log(x_c + 1e-12) --------------
__global__ void final_kernel(const float* __restrict__ classSum,
                             const int* __restrict__ classCnt,
                             float* __restrict__ out)
{
  __shared__ float red[128];
  int t = threadIdx.x;
  float total = 0.f;
  for (int c = 0; c < NCLS; ++c) total += classSum[c];
  float term = 0.f;
  if (t < NCLS) {
    int cnt = classCnt[t];
    if (cnt > 0) {
      float x = (total - classSum[t]) / (float)(N - cnt) + 1e-12f;
      term = (float)cnt * logf(x);
    }
  }
  red[t] = term;
  __syncthreads();
  for (int s = 64; s > 0; s >>= 1) {
    if (t < s) red[t] += red[t + s];
    __syncthreads();
  }
  if (t == 0) out[0] = red[0] / (float)N;
}

extern "C" void kernel_launch(void* const* d_in, const int* in_sizes, int n_in,
                              void* d_out, int out_size, void* d_ws, size_t ws_size,
                              hipStream_t stream)
{
  (void)in_sizes; (void)n_in; (void)out_size; (void)ws_size;
  const float* F = (const float*)d_in[0];
  const int* labels = (const int*)d_in[1];
  float* out = (float*)d_out;

  // ws layout: Ahi (8MB) | Alo (8MB) | m_part (512KB) | s_part (512KB) | class arrays
  char* ws = (char*)d_ws;
  u16* Ahi = (u16*)ws;
  u16* Alo = (u16*)(ws + (size_t)N * DIM * 2);
  float* m_part = (float*)(ws + (size_t)N * DIM * 4);
  float* s_part = m_part + (size_t)NPART * N;
  float* classSum = s_part + (size_t)NPART * N;
  int* classCnt = (int*)(classSum + NCLS);

  prep_kernel<<<(N * DIM) / 1024, 256, 0, stream>>>(F, Ahi, Alo, classSum, classCnt);
  gram_flash<<<64 * NSPLIT, 256, 0, stream>>>(Ahi, Alo, labels, m_part, s_part);
  combine_kernel<<<N / 256, 256, 0, stream>>>(m_part, s_part, labels, classSum, classCnt);
  final_kernel<<<1, 128, 0, stream>>>(classSum, classCnt, out);
}

// Round 2
// 221.536 us; speedup vs baseline: 1.1856x; 1.1856x over previous
//
#include <hip/hip_runtime.h>

typedef unsigned short u16;
typedef unsigned int u32;
typedef __attribute__((ext_vector_type(8))) short bfrag;   // 8 bf16 (4 VGPRs)
typedef __attribute__((ext_vector_type(4))) float facc;    // 4 fp32

#define N 8192
#define DIM 512
#define BM 128
#define BK 64
#define NTILE 2080                // 64*65/2 upper-triangular block pairs
#define NPART 64                  // one (m,s) partial per row per block-column
#define NCLS 100

#if __has_builtin(__builtin_amdgcn_exp2f)
#define EXP2(x) __builtin_amdgcn_exp2f(x)
#else
#define EXP2(x) exp2f(x)
#endif

__device__ __forceinline__ u16 f2bf(float f) {            // RNE fp32->bf16
  u32 u = __float_as_uint(f);
  u32 r = u + 0x7fffu + ((u >> 16) & 1u);
  return (u16)(r >> 16);
}
__device__ __forceinline__ float bf2f(u16 h) {
  return __uint_as_float(((u32)h) << 16);
}

// ---- prep: scale by sqrt(log2e/0.035) and split fp32 -> bf16 hi/lo --------
__global__ void prep_kernel(const float* __restrict__ F, u16* __restrict__ Ahi,
                            u16* __restrict__ Alo, float* __restrict__ classSum,
                            int* __restrict__ classCnt)
{
  const float sc = sqrtf(1.4426950408889634f / 0.035f);
  int idx = (blockIdx.x * 256 + threadIdx.x) * 4;
  float4 x = *(const float4*)(F + idx);
  float v[4] = {x.x * sc, x.y * sc, x.z * sc, x.w * sc};
  u16 h[4], l[4];
#pragma unroll
  for (int i = 0; i < 4; ++i) {
    h[i] = f2bf(v[i]);
    l[i] = f2bf(v[i] - bf2f(h[i]));
  }
  *(ushort4*)(Ahi + idx) = make_ushort4(h[0], h[1], h[2], h[3]);
  *(ushort4*)(Alo + idx) = make_ushort4(l[0], l[1], l[2], l[3]);
  if (blockIdx.x == 0 && threadIdx.x < NCLS) {
    classSum[threadIdx.x] = 0.f;
    classCnt[threadIdx.x] = 0;
  }
}

__device__ __forceinline__ void stage16(const u16* g, u16* l) {
  __builtin_amdgcn_global_load_lds((const __attribute__((address_space(1))) void*)g,
                                   (__attribute__((address_space(3))) void*)l, 16, 0, 0);
}

__device__ __forceinline__ void mergeMS(float& m, float& s, float m2, float s2) {
  float M = fmaxf(m, m2);
  s = s * EXP2(m - M) + s2 * EXP2(m2 - M);
  m = M;
}

// ---- main: symmetric flash Gram over upper-triangular tile pairs ----------
// Each block computes one 128x128 tile D[I-block, J-block] (I<=J), full K=512,
// masks in place, then reduces along BOTH axes: row-side -> partials for rows
// of I (slot J), col-side (symmetry) -> partials for rows of J (slot I).
__global__ __launch_bounds__(256, 2) void gram_flash(
    const u16* __restrict__ Ahi, const u16* __restrict__ Alo,
    const int* __restrict__ labels,
    float* __restrict__ m_part, float* __restrict__ s_part)
{
  __shared__ __align__(16) u16 lds[4 * BM * BK];   // 64 KB: ahi, alo, bhi, blo
  u16* lds_ahi = lds;
  u16* lds_alo = lds + BM * BK;
  u16* lds_bhi = lds + 2 * BM * BK;
  u16* lds_blo = lds + 3 * BM * BK;

  const int tid = threadIdx.x;
  const int wave = tid >> 6;
  const int lane = tid & 63;
  const int wr = wave >> 1, wc = wave & 1;
  const int l15 = lane & 15, lg = lane >> 4;

  // decode blockIdx -> (I, J), I<=J, off(I) = I*64 - I*(I-1)/2
  const int t = blockIdx.x;
  int I = (int)((129.0f - sqrtf(16641.0f - 8.0f * (float)t)) * 0.5f);
  while ((I + 1) * 64 - ((I + 1) * I) / 2 <= t) ++I;
  while (I * 64 - (I * (I - 1)) / 2 > t) --I;
  const int J = I + (t - (I * 64 - (I * (I - 1)) / 2));
  const int i0 = I * BM;
  const int j0 = J * BM;

  // row labels (rows of I), packed 4x8bit per mi
  u32 lr[4];
#pragma unroll
  for (int mi = 0; mi < 4; ++mi) {
    u32 pk = 0;
#pragma unroll
    for (int rg = 0; rg < 4; ++rg) {
      int r = i0 + wr * 64 + mi * 16 + lg * 4 + rg;
      pk |= ((u32)labels[r >> 1] & 0xffu) << (8 * rg);
    }
    lr[mi] = pk;
  }
  // col labels (rows of J)
  int lc[4];
#pragma unroll
  for (int ni = 0; ni < 4; ++ni)
    lc[ni] = labels[(j0 + wc * 64 + ni * 16 + l15) >> 1];

  facc acc[4][4];
#pragma unroll
  for (int a = 0; a < 4; ++a)
#pragma unroll
    for (int b = 0; b < 4; ++b)
      acc[a][b] = (facc){0.f, 0.f, 0.f, 0.f};

  for (int kk = 0; kk < DIM; kk += BK) {
    __syncthreads();
    // stage 4 tiles of [128][64] bf16; swizzle applied on the GLOBAL source
    // chunk (cg = cp ^ (row&7)), LDS dest linear (rule 21 both-sides).
#pragma unroll
    for (int q = 0; q < 4; ++q) {
      const int ci = (wave * 4 + q) * 64 + lane;
      const int row = ci >> 3;
      const int cp = ci & 7;
      const int cg = cp ^ (row & 7);
      const size_t goffA = (size_t)(i0 + row) * DIM + kk + cg * 8;
      const size_t goffB = (size_t)(j0 + row) * DIM + kk + cg * 8;
      const int lbase = (wave * 4 + q) * 512;
      stage16(Ahi + goffA, lds_ahi + lbase);
      stage16(Alo + goffA, lds_alo + lbase);
      stage16(Ahi + goffB, lds_bhi + lbase);
      stage16(Alo + goffB, lds_blo + lbase);
    }
    asm volatile("s_waitcnt vmcnt(0)" ::: "memory");
    __syncthreads();

#pragma unroll
    for (int k2 = 0; k2 < 2; ++k2) {
      bfrag fah[4], fal[4], fbh[4], fbl[4];
#pragma unroll
      for (int mi = 0; mi < 4; ++mi) {
        const int row = wr * 64 + mi * 16 + l15;
        const int cc = (k2 * 4 + lg) ^ (row & 7);   // un-swizzle on read
        const int off = row * 64 + cc * 8;
        fah[mi] = *(const bfrag*)(lds_ahi + off);
        fal[mi] = *(const bfrag*)(lds_alo + off);
      }
#pragma unroll
      for (int ni = 0; ni < 4; ++ni) {
        const int row = wc * 64 + ni * 16 + l15;
        const int cc = (k2 * 4 + lg) ^ (row & 7);
        const int off = row * 64 + cc * 8;
        fbh[ni] = *(const bfrag*)(lds_bhi + off);
        fbl[ni] = *(const bfrag*)(lds_blo + off);
      }
#pragma unroll
      for (int mi = 0; mi < 4; ++mi)
#pragma unroll
        for (int ni = 0; ni < 4; ++ni)
          acc[mi][ni] = __builtin_amdgcn_mfma_f32_16x16x32_bf16(fah[mi], fbh[ni], acc[mi][ni], 0, 0, 0);
#pragma unroll
      for (int mi = 0; mi < 4; ++mi)
#pragma unroll
        for (int ni = 0; ni < 4; ++ni)
          acc[mi][ni] = __builtin_amdgcn_mfma_f32_16x16x32_bf16(fah[mi], fbl[ni], acc[mi][ni], 0, 0, 0);
#pragma unroll
      for (int mi = 0; mi < 4; ++mi)
#pragma unroll
        for (int ni = 0; ni < 4; ++ni)
          acc[mi][ni] = __builtin_amdgcn_mfma_f32_16x16x32_bf16(fal[mi], fbh[ni], acc[mi][ni], 0, 0, 0);
    }
  }

  // mask in place: same-class pairs -> -1e30 (exp2 underflows to 0)
#pragma unroll
  for (int mi = 0; mi < 4; ++mi)
#pragma unroll
    for (int rg = 0; rg < 4; ++rg) {
      const int labr = (int)((lr[mi] >> (8 * rg)) & 0xffu);
#pragma unroll
      for (int ni = 0; ni < 4; ++ni)
        if (labr == lc[ni]) acc[mi][ni][rg] = -1e30f;
    }

  // row-side reduction: per row (mi,rg), max/sum-exp2 over 4 ni, then
  // butterfly over the 16 l15 lanes (cols) -> (m,s) per row over 64 cols
  float rm[16], rs[16];
#pragma unroll
  for (int mi = 0; mi < 4; ++mi)
#pragma unroll
    for (int rg = 0; rg < 4; ++rg) {
      const int si = mi * 4 + rg;
      float m = -1e20f;
#pragma unroll
      for (int ni = 0; ni < 4; ++ni) m = fmaxf(m, acc[mi][ni][rg]);
      float s = 0.f;
#pragma unroll
      for (int ni = 0; ni < 4; ++ni) s += EXP2(acc[mi][ni][rg] - m);
      rm[si] = m; rs[si] = s;
    }
#pragma unroll
  for (int st = 1; st <= 8; st <<= 1)
#pragma unroll
    for (int si = 0; si < 16; ++si)
      mergeMS(rm[si], rs[si], __shfl_xor(rm[si], st, 64), __shfl_xor(rs[si], st, 64));

  // col-side reduction (symmetry): per col ni, max/sum-exp2 over 16 (mi,rg),
  // then butterfly over the 4 lg lanes (rows)
  float cm[4], cs[4];
#pragma unroll
  for (int ni = 0; ni < 4; ++ni) {
    float m = -1e20f;
#pragma unroll
    for (int mi = 0; mi < 4; ++mi)
#pragma unroll
      for (int rg = 0; rg < 4; ++rg) m = fmaxf(m, acc[mi][ni][rg]);
    float s = 0.f;
#pragma unroll
    for (int mi = 0; mi < 4; ++mi)
#pragma unroll
      for (int rg = 0; rg < 4; ++rg) s += EXP2(acc[mi][ni][rg] - m);
    cm[ni] = m; cs[ni] = s;
  }
#pragma unroll
  for (int st = 16; st <= 32; st <<= 1)
#pragma unroll
    for (int ni = 0; ni < 4; ++ni)
      mergeMS(cm[ni], cs[ni], __shfl_xor(cm[ni], st, 64), __shfl_xor(cs[ni], st, 64));

  // cross-wave merge via LDS (reuse staging buffer): [wc][128] row-side,
  // [wr][128] col-side
  float* buf = (float*)lds;
  float* RM = buf;            // [2][128]
  float* RS = buf + 256;
  float* CM = buf + 512;
  float* CS = buf + 768;

  __syncthreads();   // all waves done with staging LDS reads
  if (l15 == 0) {
#pragma unroll
    for (int mi = 0; mi < 4; ++mi)
#pragma unroll
      for (int rg = 0; rg < 4; ++rg) {
        const int idx = wr * 64 + mi * 16 + lg * 4 + rg;
        RM[wc * 128 + idx] = rm[mi * 4 + rg];
        RS[wc * 128 + idx] = rs[mi * 4 + rg];
      }
  }
  if (lg == 0 && I != J) {
#pragma unroll
    for (int ni = 0; ni < 4; ++ni) {
      const int c = wc * 64 + ni * 16 + l15;
      CM[wr * 128 + c] = cm[ni];
      CS[wr * 128 + c] = cs[ni];
    }
  }
  __syncthreads();

  if (tid < 128) {                       // rows of I -> slot J
    float m = RM[tid], s = RS[tid];
    mergeMS(m, s, RM[128 + tid], RS[128 + tid]);
    m_part[(size_t)J * N + i0 + tid] = m;
    s_part[(size_t)J * N + i0 + tid] = s;
  } else if (I != J) {                   // rows of J (cols) -> slot I
    const int c = tid - 128;
    float m = CM[c], s = CS[c];
    mergeMS(m, s, CM[128 + c], CS[128 + c]);
    m_part[(size_t)I * N + j0 + c] = m;
    s_part[(size_t)I * N + j0 + c] = s;
  }
}

// ---- combine the 64 partials per row, accumulate per-class sums -----------
__global__ void combine_kernel(const float* __restrict__ m_part,
                               const float* __restrict__ s_part,
                               const int* __restrict__ labels,
                               float* __restrict__ classSum,
                               int* __restrict__ classCnt)
{
  int j = blockIdx.x * 256 + threadIdx.x;
  float M = -1e20f;
  for (int p = 0; p < NPART; ++p) M = fmaxf(M, m_part[p * N + j]);
  float S = 0.f;
  for (int p = 0; p < NPART; ++p)
    S += s_part[p * N + j] * EXP2(m_part[p * N + j] - M);
  int c = labels[j >> 1];
  atomicAdd(&classSum[c], S);
  atomicAdd(&classCnt[c], 1);
}

// ---- finalize: loss = (1/N) * sum_c cnt_c * log(x_c + 1e-12) --------------
__global__ void final_kernel(const float* __restrict__ classSum,
                             const int* __restrict__ classCnt,
                             float* __restrict__ out)
{
  __shared__ float red[128];
  int t = threadIdx.x;
  float total = 0.f;
  for (int c = 0; c < NCLS; ++c) total += classSum[c];
  float term = 0.f;
  if (t < NCLS) {
    int cnt = classCnt[t];
    if (cnt > 0) {
      float x = (total - classSum[t]) / (float)(N - cnt) + 1e-12f;
      term = (float)cnt * logf(x);
    }
  }
  red[t] = term;
  __syncthreads();
  for (int s = 64; s > 0; s >>= 1) {
    if (t < s) red[t] += red[t + s];
    __syncthreads();
  }
  if (t == 0) out[0] = red[0] / (float)N;
}

extern "C" void kernel_launch(void* const* d_in, const int* in_sizes, int n_in,
                              void* d_out, int out_size, void* d_ws, size_t ws_size,
                              hipStream_t stream)
{
  (void)in_sizes; (void)n_in; (void)out_size; (void)ws_size;
  const float* F = (const float*)d_in[0];
  const int* labels = (const int*)d_in[1];
  float* out = (float*)d_out;

  // ws: Ahi (8MB) | Alo (8MB) | m_part (2MB) | s_part (2MB) | class arrays
  char* ws = (char*)d_ws;
  u16* Ahi = (u16*)ws;
  u16* Alo = (u16*)(ws + (size_t)N * DIM * 2);
  float* m_part = (float*)(ws + (size_t)N * DIM * 4);
  float* s_part = m_part + (size_t)NPART * N;
  float* classSum = s_part + (size_t)NPART * N;
  int* classCnt = (int*)(classSum + NCLS);

  prep_kernel<<<(N * DIM) / 1024, 256, 0, stream>>>(F, Ahi, Alo, classSum, classCnt);
  gram_flash<<<NTILE, 256, 0, stream>>>(Ahi, Alo, labels, m_part, s_part);
  combine_kernel<<<N / 256, 256, 0, stream>>>(m_part, s_part, labels, classSum, classCnt);
  final_kernel<<<1, 128, 0, stream>>>(classSum, classCnt, out);
}

// Round 3
// 220.443 us; speedup vs baseline: 1.1914x; 1.0050x over previous
//
#include <hip/hip_runtime.h>

typedef unsigned short u16;
typedef unsigned int u32;
typedef __attribute__((ext_vector_type(8))) short bfrag;   // 8 bf16 (4 VGPRs)
typedef __attribute__((ext_vector_type(4))) float facc;    // 4 fp32

#define N 8192
#define DIM 512
#define BM 128
#define BK 32
#define NTILE 2080                // 64*65/2 upper-triangular block pairs
#define NPART 64                  // one (m,s) partial per row per block-column
#define NCLS 100
#define TPX 260                   // tiles per XCD chunk (2080/8)

#if __has_builtin(__builtin_amdgcn_exp2f)
#define EXP2(x) __builtin_amdgcn_exp2f(x)
#else
#define EXP2(x) exp2f(x)
#endif

__device__ __forceinline__ u16 f2bf(float f) {            // RNE fp32->bf16
  u32 u = __float_as_uint(f);
  u32 r = u + 0x7fffu + ((u >> 16) & 1u);
  return (u16)(r >> 16);
}
__device__ __forceinline__ float bf2f(u16 h) {
  return __uint_as_float(((u32)h) << 16);
}

// ---- prep: scale by sqrt(log2e/0.035) and split fp32 -> bf16 hi/lo --------
__global__ void prep_kernel(const float* __restrict__ F, u16* __restrict__ Ahi,
                            u16* __restrict__ Alo, float* __restrict__ classSum,
                            int* __restrict__ classCnt)
{
  const float sc = sqrtf(1.4426950408889634f / 0.035f);
  int idx = (blockIdx.x * 256 + threadIdx.x) * 4;
  float4 x = *(const float4*)(F + idx);
  float v[4] = {x.x * sc, x.y * sc, x.z * sc, x.w * sc};
  u16 h[4], l[4];
#pragma unroll
  for (int i = 0; i < 4; ++i) {
    h[i] = f2bf(v[i]);
    l[i] = f2bf(v[i] - bf2f(h[i]));
  }
  *(ushort4*)(Ahi + idx) = make_ushort4(h[0], h[1], h[2], h[3]);
  *(ushort4*)(Alo + idx) = make_ushort4(l[0], l[1], l[2], l[3]);
  if (blockIdx.x == 0 && threadIdx.x < NCLS) {
    classSum[threadIdx.x] = 0.f;
    classCnt[threadIdx.x] = 0;
  }
}

__device__ __forceinline__ void stage16(const u16* g, u16* l) {
  __builtin_amdgcn_global_load_lds((const __attribute__((address_space(1))) void*)g,
                                   (__attribute__((address_space(3))) void*)l, 16, 0, 0);
}

__device__ __forceinline__ void mergeMS(float& m, float& s, float m2, float s2) {
  float M = fmaxf(m, m2);
  s = s * EXP2(m - M) + s2 * EXP2(m2 - M);
  m = M;
}

// ---- main: symmetric flash Gram, supertile order, 4 blocks/CU -------------
// Tile = 128x128 of D (I<=J). BK=32, LDS 32KB (4 x 8KB tiles).
// LDS layout per tile: 64 lines x 128B; line L holds rows 2L,2L+1 (4 chunks
// of 16B each, cb = (row&1)*4 + kchunk), stored chunk = cb ^ (L&7).
// -> ds_read_b128 fragment reads are 2-way-bank max (free); staging applies
// the inverse permutation on the GLOBAL source address (rule 21 both-sides).
__global__ __launch_bounds__(256, 4) void gram_flash(
    const u16* __restrict__ Ahi, const u16* __restrict__ Alo,
    const int* __restrict__ labels,
    float* __restrict__ m_part, float* __restrict__ s_part)
{
  __shared__ __align__(16) u16 lds[4 * BM * BK];   // 32 KB
  u16* lds_ahi = lds;
  u16* lds_alo = lds + BM * BK;
  u16* lds_bhi = lds + 2 * BM * BK;
  u16* lds_blo = lds + 3 * BM * BK;

  const int tid = threadIdx.x;
  const int wave = tid >> 6;
  const int lane = tid & 63;
  const int wr = wave >> 1, wc = wave & 1;
  const int l15 = lane & 15, lg = lane >> 4;

  // ---- blockIdx -> tile id (XCD-chunked, supertile-major) ----
  const int t = (blockIdx.x & 7) * TPX + (blockIdx.x >> 3);
  // supertile row SI: counts 36 + (7-SI)*64 per row
  int SI = 0, base = 0;
  for (;; ++SI) {
    int rowcnt = 36 + (7 - SI) * 64;
    if (t < base + rowcnt) break;
    base += rowcnt;
  }
  const int r = t - base;
  int SJ, li, lj;
  if (r < 36) {                      // diagonal supertile: local 8x8 triangle
    SJ = SI;
    int a = 0, cum = 0;
    for (;; ++a) { if (r < cum + (8 - a)) break; cum += 8 - a; }
    li = a; lj = a + (r - cum);
  } else {                           // off-diagonal supertiles, row-major
    int rr = r - 36;
    SJ = SI + 1 + (rr >> 6);
    li = (rr & 63) >> 3;
    lj = rr & 7;
  }
  const int I = SI * 8 + li, J = SJ * 8 + lj;
  const int i0 = I * BM;
  const int j0 = J * BM;

  // row labels (rows of I), packed 4x8bit per mi
  u32 lr[4];
#pragma unroll
  for (int mi = 0; mi < 4; ++mi) {
    u32 pk = 0;
#pragma unroll
    for (int rg = 0; rg < 4; ++rg) {
      int rr2 = i0 + wr * 64 + mi * 16 + lg * 4 + rg;
      pk |= ((u32)labels[rr2 >> 1] & 0xffu) << (8 * rg);
    }
    lr[mi] = pk;
  }
  // col labels (rows of J)
  int lc[4];
#pragma unroll
  for (int ni = 0; ni < 4; ++ni)
    lc[ni] = labels[(j0 + wc * 64 + ni * 16 + l15) >> 1];

  facc acc[4][4];
#pragma unroll
  for (int a = 0; a < 4; ++a)
#pragma unroll
    for (int b = 0; b < 4; ++b)
      acc[a][b] = (facc){0.f, 0.f, 0.f, 0.f};

  for (int kk = 0; kk < DIM; kk += BK) {
    __syncthreads();                 // previous step's ds_reads done
#pragma unroll
    for (int q = 0; q < 2; ++q) {
      const int ci = (wave * 2 + q) * 64 + lane;   // 16B-chunk index 0..511
      const int L = ci >> 3;                       // LDS line
      const int sc2 = ci & 7;                      // stored chunk
      const int cb = sc2 ^ (L & 7);                // logical chunk
      const int row = L * 2 + (cb >> 2);
      const int kc = cb & 3;
      const size_t goffA = (size_t)(i0 + row) * DIM + kk + kc * 8;
      const size_t goffB = (size_t)(j0 + row) * DIM + kk + kc * 8;
      const int lbase = (wave * 2 + q) * 512;      // u16 units
      stage16(Ahi + goffA, lds_ahi + lbase);
      stage16(Alo + goffA, lds_alo + lbase);
      stage16(Ahi + goffB, lds_bhi + lbase);
      stage16(Alo + goffB, lds_blo + lbase);
    }
    asm volatile("s_waitcnt vmcnt(0)" ::: "memory");
    __syncthreads();

    bfrag fah[4], fal[4], fbh[4], fbl[4];
#pragma unroll
    for (int mi = 0; mi < 4; ++mi) {
      const int row = wr * 64 + mi * 16 + l15;
      const int L = row >> 1;
      const int cb = ((row & 1) << 2) | lg;
      const int off = L * 64 + (cb ^ (L & 7)) * 8; // u16 units (line=64 u16)
      fah[mi] = *(const bfrag*)(lds_ahi + off);
      fal[mi] = *(const bfrag*)(lds_alo + off);
    }
#pragma unroll
    for (int ni = 0; ni < 4; ++ni) {
      const int row = wc * 64 + ni * 16 + l15;
      const int L = row >> 1;
      const int cb = ((row & 1) << 2) | lg;
      const int off = L * 64 + (cb ^ (L & 7)) * 8;
      fbh[ni] = *(const bfrag*)(lds_bhi + off);
      fbl[ni] = *(const bfrag*)(lds_blo + off);
    }
#pragma unroll
    for (int mi = 0; mi < 4; ++mi)
#pragma unroll
      for (int ni = 0; ni < 4; ++ni)
        acc[mi][ni] = __builtin_amdgcn_mfma_f32_16x16x32_bf16(fah[mi], fbh[ni], acc[mi][ni], 0, 0, 0);
#pragma unroll
    for (int mi = 0; mi < 4; ++mi)
#pragma unroll
      for (int ni = 0; ni < 4; ++ni)
        acc[mi][ni] = __builtin_amdgcn_mfma_f32_16x16x32_bf16(fah[mi], fbl[ni], acc[mi][ni], 0, 0, 0);
#pragma unroll
    for (int mi = 0; mi < 4; ++mi)
#pragma unroll
      for (int ni = 0; ni < 4; ++ni)
        acc[mi][ni] = __builtin_amdgcn_mfma_f32_16x16x32_bf16(fal[mi], fbh[ni], acc[mi][ni], 0, 0, 0);
  }

  // mask in place: same-class pairs -> -1e30 (exp2 underflows to 0)
#pragma unroll
  for (int mi = 0; mi < 4; ++mi)
#pragma unroll
    for (int rg = 0; rg < 4; ++rg) {
      const int labr = (int)((lr[mi] >> (8 * rg)) & 0xffu);
#pragma unroll
      for (int ni = 0; ni < 4; ++ni)
        if (labr == lc[ni]) acc[mi][ni][rg] = -1e30f;
    }

  // row-side reduction -> (m,s) per row of I over these 64 cols
  float rm[16], rs[16];
#pragma unroll
  for (int mi = 0; mi < 4; ++mi)
#pragma unroll
    for (int rg = 0; rg < 4; ++rg) {
      const int si = mi * 4 + rg;
      float m = -1e20f;
#pragma unroll
      for (int ni = 0; ni < 4; ++ni) m = fmaxf(m, acc[mi][ni][rg]);
      float s = 0.f;
#pragma unroll
      for (int ni = 0; ni < 4; ++ni) s += EXP2(acc[mi][ni][rg] - m);
      rm[si] = m; rs[si] = s;
    }
#pragma unroll
  for (int st = 1; st <= 8; st <<= 1)
#pragma unroll
    for (int si = 0; si < 16; ++si)
      mergeMS(rm[si], rs[si], __shfl_xor(rm[si], st, 64), __shfl_xor(rs[si], st, 64));

  // col-side reduction (symmetry) -> (m,s) per row of J over these 64 rows
  float cm[4], cs[4];
#pragma unroll
  for (int ni = 0; ni < 4; ++ni) {
    float m = -1e20f;
#pragma unroll
    for (int mi = 0; mi < 4; ++mi)
#pragma unroll
      for (int rg = 0; rg < 4; ++rg) m = fmaxf(m, acc[mi][ni][rg]);
    float s = 0.f;
#pragma unroll
    for (int mi = 0; mi < 4; ++mi)
#pragma unroll
      for (int rg = 0; rg < 4; ++rg) s += EXP2(acc[mi][ni][rg] - m);
    cm[ni] = m; cs[ni] = s;
  }
#pragma unroll
  for (int st = 16; st <= 32; st <<= 1)
#pragma unroll
    for (int ni = 0; ni < 4; ++ni)
      mergeMS(cm[ni], cs[ni], __shfl_xor(cm[ni], st, 64), __shfl_xor(cs[ni], st, 64));

  // cross-wave merge via LDS (reuse staging buffer)
  float* buf = (float*)lds;
  float* RM = buf;            // [2][128]
  float* RS = buf + 256;
  float* CM = buf + 512;
  float* CS = buf + 768;

  __syncthreads();
  if (l15 == 0) {
#pragma unroll
    for (int mi = 0; mi < 4; ++mi)
#pragma unroll
      for (int rg = 0; rg < 4; ++rg) {
        const int idx = wr * 64 + mi * 16 + lg * 4 + rg;
        RM[wc * 128 + idx] = rm[mi * 4 + rg];
        RS[wc * 128 + idx] = rs[mi * 4 + rg];
      }
  }
  if (lg == 0 && I != J) {
#pragma unroll
    for (int ni = 0; ni < 4; ++ni) {
      const int c = wc * 64 + ni * 16 + l15;
      CM[wr * 128 + c] = cm[ni];
      CS[wr * 128 + c] = cs[ni];
    }
  }
  __syncthreads();

  if (tid < 128) {                       // rows of I -> slot J
    float m = RM[tid], s = RS[tid];
    mergeMS(m, s, RM[128 + tid], RS[128 + tid]);
    m_part[(size_t)J * N + i0 + tid] = m;
    s_part[(size_t)J * N + i0 + tid] = s;
  } else if (I != J) {                   // rows of J (cols) -> slot I
    const int c = tid - 128;
    float m = CM[c], s = CS[c];
    mergeMS(m, s, CM[128 + c], CS[128 + c]);
    m_part[(size_t)I * N + j0 + c] = m;
    s_part[(size_t)I * N + j0 + c] = s;
  }
}

// ---- combine the 64 partials per row, accumulate per-class sums -----------
__global__ void combine_kernel(const float* __restrict__ m_part,
                               const float* __restrict__ s_part,
                               const int* __restrict__ labels,
                               float* __restrict__ classSum,
                               int* __restrict__ classCnt)
{
  int j = blockIdx.x * 256 + threadIdx.x;
  float M = -1e20f;
  for (int p = 0; p < NPART; ++p) M = fmaxf(M, m_part[p * N + j]);
  float S = 0.f;
  for (int p = 0; p < NPART; ++p)
    S += s_part[p * N + j] * EXP2(m_part[p * N + j] - M);
  int c = labels[j >> 1];
  atomicAdd(&classSum[c], S);
  atomicAdd(&classCnt[c], 1);
}

// ---- finalize: loss = (1/N) * sum_c cnt_c * log(x_c + 1e-12) --------------
__global__ void final_kernel(const float* __restrict__ classSum,
                             const int* __restrict__ classCnt,
                             float* __restrict__ out)
{
  __shared__ float red[128];
  int t = threadIdx.x;
  float total = 0.f;
  for (int c = 0; c < NCLS; ++c) total += classSum[c];
  float term = 0.f;
  if (t < NCLS) {
    int cnt = classCnt[t];
    if (cnt > 0) {
      float x = (total - classSum[t]) / (float)(N - cnt) + 1e-12f;
      term = (float)cnt * logf(x);
    }
  }
  red[t] = term;
  __syncthreads();
  for (int s = 64; s > 0; s >>= 1) {
    if (t < s) red[t] += red[t + s];
    __syncthreads();
  }
  if (t == 0) out[0] = red[0] / (float)N;
}

extern "C" void kernel_launch(void* const* d_in, const int* in_sizes, int n_in,
                              void* d_out, int out_size, void* d_ws, size_t ws_size,
                              hipStream_t stream)
{
  (void)in_sizes; (void)n_in; (void)out_size; (void)ws_size;
  const float* F = (const float*)d_in[0];
  const int* labels = (const int*)d_in[1];
  float* out = (float*)d_out;

  // ws: Ahi (8MB) | Alo (8MB) | m_part (2MB) | s_part (2MB) | class arrays
  char* ws = (char*)d_ws;
  u16* Ahi = (u16*)ws;
  u16* Alo = (u16*)(ws + (size_t)N * DIM * 2);
  float* m_part = (float*)(ws + (size_t)N * DIM * 4);
  float* s_part = m_part + (size_t)NPART * N;
  float* classSum = s_part + (size_t)NPART * N;
  int* classCnt = (int*)(classSum + NCLS);

  prep_kernel<<<(N * DIM) / 1024, 256, 0, stream>>>(F, Ahi, Alo, classSum, classCnt);
  gram_flash<<<NTILE, 256, 0, stream>>>(Ahi, Alo, labels, m_part, s_part);
  combine_kernel<<<N / 256, 256, 0, stream>>>(m_part, s_part, labels, classSum, classCnt);
  final_kernel<<<1, 128, 0, stream>>>(classSum, classCnt, out);
}

// Round 4
// 207.975 us; speedup vs baseline: 1.2629x; 1.0600x over previous
//
#include <hip/hip_runtime.h>

typedef unsigned short u16;
typedef unsigned int u32;
typedef __attribute__((ext_vector_type(8))) short bfrag;   // 8 bf16 (4 VGPRs)
typedef __attribute__((ext_vector_type(4))) float facc;    // 4 fp32

#define N 8192
#define DIM 512
#define BM 128
#define BK 64
#define NTILE 2080                // 64*65/2 upper-triangular block pairs
#define NPART 64                  // one (m,s) partial per row per block-column
#define NCLS 100
#define TPX 260                   // tiles per XCD chunk (2080/8)

#if __has_builtin(__builtin_amdgcn_exp2f)
#define EXP2(x) __builtin_amdgcn_exp2f(x)
#else
#define EXP2(x) exp2f(x)
#endif

__device__ __forceinline__ u16 f2bf(float f) {            // RNE fp32->bf16
  u32 u = __float_as_uint(f);
  u32 r = u + 0x7fffu + ((u >> 16) & 1u);
  return (u16)(r >> 16);
}
__device__ __forceinline__ float bf2f(u16 h) {
  return __uint_as_float(((u32)h) << 16);
}

// ---- prep: scale by sqrt(log2e/0.035) and split fp32 -> bf16 hi/lo --------
__global__ void prep_kernel(const float* __restrict__ F, u16* __restrict__ Ahi,
                            u16* __restrict__ Alo, float* __restrict__ classSum,
                            int* __restrict__ classCnt)
{
  const float sc = sqrtf(1.4426950408889634f / 0.035f);
  int idx = (blockIdx.x * 256 + threadIdx.x) * 4;
  float4 x = *(const float4*)(F + idx);
  float v[4] = {x.x * sc, x.y * sc, x.z * sc, x.w * sc};
  u16 h[4], l[4];
#pragma unroll
  for (int i = 0; i < 4; ++i) {
    h[i] = f2bf(v[i]);
    l[i] = f2bf(v[i] - bf2f(h[i]));
  }
  *(ushort4*)(Ahi + idx) = make_ushort4(h[0], h[1], h[2], h[3]);
  *(ushort4*)(Alo + idx) = make_ushort4(l[0], l[1], l[2], l[3]);
  if (blockIdx.x == 0 && threadIdx.x < NCLS) {
    classSum[threadIdx.x] = 0.f;
    classCnt[threadIdx.x] = 0;
  }
}

__device__ __forceinline__ void stage16(const u16* g, u16* l) {
  __builtin_amdgcn_global_load_lds((const __attribute__((address_space(1))) void*)g,
                                   (__attribute__((address_space(3))) void*)l, 16, 0, 0);
}

__device__ __forceinline__ void mergeMS(float& m, float& s, float m2, float s2) {
  float M = fmaxf(m, m2);
  s = s * EXP2(m - M) + s2 * EXP2(m2 - M);
  m = M;
}

// ---- main: symmetric flash Gram, BK=64 (96 MFMA/barrier), supertile order -
// Tile = 128x128 of D (I<=J), K=512 in 8 steps of BK=64. LDS 64KB.
// Bank swizzle: stored chunk = logical chunk ^ (row&7), applied on the GLOBAL
// source address at staging, undone on ds_read (rule 21 both-sides; 0 conflicts
// measured in rounds 1-3).
__global__ __launch_bounds__(256, 2) void gram_flash(
    const u16* __restrict__ Ahi, const u16* __restrict__ Alo,
    const int* __restrict__ labels,
    float* __restrict__ m_part, float* __restrict__ s_part)
{
  __shared__ __align__(16) u16 lds[4 * BM * BK];   // 64 KB: ahi, alo, bhi, blo
  u16* lds_ahi = lds;
  u16* lds_alo = lds + BM * BK;
  u16* lds_bhi = lds + 2 * BM * BK;
  u16* lds_blo = lds + 3 * BM * BK;

  const int tid = threadIdx.x;
  const int wave = tid >> 6;
  const int lane = tid & 63;
  const int wr = wave >> 1, wc = wave & 1;
  const int l15 = lane & 15, lg = lane >> 4;

  // ---- blockIdx -> tile id (XCD-chunked, supertile-major; round-3 proven) --
  const int t = (blockIdx.x & 7) * TPX + (blockIdx.x >> 3);
  int SI = 0, base = 0;
  for (;; ++SI) {                        // supertile row: 36 + (7-SI)*64 tiles
    int rowcnt = 36 + (7 - SI) * 64;
    if (t < base + rowcnt) break;
    base += rowcnt;
  }
  const int r = t - base;
  int SJ, li, lj;
  if (r < 36) {                          // diagonal supertile: 8x8 triangle
    SJ = SI;
    int a = 0, cum = 0;
    for (;; ++a) { if (r < cum + (8 - a)) break; cum += 8 - a; }
    li = a; lj = a + (r - cum);
  } else {                               // off-diagonal supertiles, row-major
    int rr = r - 36;
    SJ = SI + 1 + (rr >> 6);
    li = (rr & 63) >> 3;
    lj = rr & 7;
  }
  const int I = SI * 8 + li, J = SJ * 8 + lj;
  const int i0 = I * BM;
  const int j0 = J * BM;

  // row labels (rows of I), packed 4x8bit per mi
  u32 lr[4];
#pragma unroll
  for (int mi = 0; mi < 4; ++mi) {
    u32 pk = 0;
#pragma unroll
    for (int rg = 0; rg < 4; ++rg) {
      int rr2 = i0 + wr * 64 + mi * 16 + lg * 4 + rg;
      pk |= ((u32)labels[rr2 >> 1] & 0xffu) << (8 * rg);
    }
    lr[mi] = pk;
  }
  // col labels (rows of J)
  int lc[4];
#pragma unroll
  for (int ni = 0; ni < 4; ++ni)
    lc[ni] = labels[(j0 + wc * 64 + ni * 16 + l15) >> 1];

  facc acc[4][4];
#pragma unroll
  for (int a = 0; a < 4; ++a)
#pragma unroll
    for (int b = 0; b < 4; ++b)
      acc[a][b] = (facc){0.f, 0.f, 0.f, 0.f};

  for (int kk = 0; kk < DIM; kk += BK) {
    __syncthreads();                     // prev step's ds_reads done
#pragma unroll
    for (int q = 0; q < 4; ++q) {
      const int ci = (wave * 4 + q) * 64 + lane;   // 16B-chunk index 0..1023
      const int row = ci >> 3;                     // 0..127
      const int cp = ci & 7;                       // linear dest chunk
      const int cg = cp ^ (row & 7);               // swizzled source chunk
      const size_t goffA = (size_t)(i0 + row) * DIM + kk + cg * 8;
      const size_t goffB = (size_t)(j0 + row) * DIM + kk + cg * 8;
      const int lbase = (wave * 4 + q) * 512;      // u16 units
      stage16(Ahi + goffA, lds_ahi + lbase);
      stage16(Alo + goffA, lds_alo + lbase);
      stage16(Ahi + goffB, lds_bhi + lbase);
      stage16(Alo + goffB, lds_blo + lbase);
    }
    asm volatile("s_waitcnt vmcnt(0)" ::: "memory");
    __syncthreads();

#pragma unroll
    for (int k2 = 0; k2 < 2; ++k2) {
      bfrag fah[4], fal[4], fbh[4], fbl[4];
#pragma unroll
      for (int mi = 0; mi < 4; ++mi) {
        const int row = wr * 64 + mi * 16 + l15;
        const int cc = (k2 * 4 + lg) ^ (row & 7);  // un-swizzle on read
        const int off = row * 64 + cc * 8;
        fah[mi] = *(const bfrag*)(lds_ahi + off);
        fal[mi] = *(const bfrag*)(lds_alo + off);
      }
#pragma unroll
      for (int ni = 0; ni < 4; ++ni) {
        const int row = wc * 64 + ni * 16 + l15;
        const int cc = (k2 * 4 + lg) ^ (row & 7);
        const int off = row * 64 + cc * 8;
        fbh[ni] = *(const bfrag*)(lds_bhi + off);
        fbl[ni] = *(const bfrag*)(lds_blo + off);
      }
#pragma unroll
      for (int mi = 0; mi < 4; ++mi)
#pragma unroll
        for (int ni = 0; ni < 4; ++ni)
          acc[mi][ni] = __builtin_amdgcn_mfma_f32_16x16x32_bf16(fah[mi], fbh[ni], acc[mi][ni], 0, 0, 0);
#pragma unroll
      for (int mi = 0; mi < 4; ++mi)
#pragma unroll
        for (int ni = 0; ni < 4; ++ni)
          acc[mi][ni] = __builtin_amdgcn_mfma_f32_16x16x32_bf16(fah[mi], fbl[ni], acc[mi][ni], 0, 0, 0);
#pragma unroll
      for (int mi = 0; mi < 4; ++mi)
#pragma unroll
        for (int ni = 0; ni < 4; ++ni)
          acc[mi][ni] = __builtin_amdgcn_mfma_f32_16x16x32_bf16(fal[mi], fbh[ni], acc[mi][ni], 0, 0, 0);
    }
  }

  // mask in place: same-class pairs -> -1e30 (exp2 underflows to 0)
#pragma unroll
  for (int mi = 0; mi < 4; ++mi)
#pragma unroll
    for (int rg = 0; rg < 4; ++rg) {
      const int labr = (int)((lr[mi] >> (8 * rg)) & 0xffu);
#pragma unroll
      for (int ni = 0; ni < 4; ++ni)
        if (labr == lc[ni]) acc[mi][ni][rg] = -1e30f;
    }

  // row-side reduction -> (m,s) per row of I over these 64 cols
  float rm[16], rs[16];
#pragma unroll
  for (int mi = 0; mi < 4; ++mi)
#pragma unroll
    for (int rg = 0; rg < 4; ++rg) {
      const int si = mi * 4 + rg;
      float m = -1e20f;
#pragma unroll
      for (int ni = 0; ni < 4; ++ni) m = fmaxf(m, acc[mi][ni][rg]);
      float s = 0.f;
#pragma unroll
      for (int ni = 0; ni < 4; ++ni) s += EXP2(acc[mi][ni][rg] - m);
      rm[si] = m; rs[si] = s;
    }
#pragma unroll
  for (int st = 1; st <= 8; st <<= 1)
#pragma unroll
    for (int si = 0; si < 16; ++si)
      mergeMS(rm[si], rs[si], __shfl_xor(rm[si], st, 64), __shfl_xor(rs[si], st, 64));

  // col-side reduction (symmetry) -> (m,s) per row of J over these 64 rows
  float cm[4], cs[4];
#pragma unroll
  for (int ni = 0; ni < 4; ++ni) {
    float m = -1e20f;
#pragma unroll
    for (int mi = 0; mi < 4; ++mi)
#pragma unroll
      for (int rg = 0; rg < 4; ++rg) m = fmaxf(m, acc[mi][ni][rg]);
    float s = 0.f;
#pragma unroll
    for (int mi = 0; mi < 4; ++mi)
#pragma unroll
      for (int rg = 0; rg < 4; ++rg) s += EXP2(acc[mi][ni][rg] - m);
    cm[ni] = m; cs[ni] = s;
  }
#pragma unroll
  for (int st = 16; st <= 32; st <<= 1)
#pragma unroll
    for (int ni = 0; ni < 4; ++ni)
      mergeMS(cm[ni], cs[ni], __shfl_xor(cm[ni], st, 64), __shfl_xor(cs[ni], st, 64));

  // cross-wave merge via LDS (reuse staging buffer)
  float* buf = (float*)lds;
  float* RM = buf;            // [2][128]
  float* RS = buf + 256;
  float* CM = buf + 512;
  float* CS = buf + 768;

  __syncthreads();
  if (l15 == 0) {
#pragma unroll
    for (int mi = 0; mi < 4; ++mi)
#pragma unroll
      for (int rg = 0; rg < 4; ++rg) {
        const int idx = wr * 64 + mi * 16 + lg * 4 + rg;
        RM[wc * 128 + idx] = rm[mi * 4 + rg];
        RS[wc * 128 + idx] = rs[mi * 4 + rg];
      }
  }
  if (lg == 0 && I != J) {
#pragma unroll
    for (int ni = 0; ni < 4; ++ni) {
      const int c = wc * 64 + ni * 16 + l15;
      CM[wr * 128 + c] = cm[ni];
      CS[wr * 128 + c] = cs[ni];
    }
  }
  __syncthreads();

  if (tid < 128) {                       // rows of I -> slot J
    float m = RM[tid], s = RS[tid];
    mergeMS(m, s, RM[128 + tid], RS[128 + tid]);
    m_part[(size_t)J * N + i0 + tid] = m;
    s_part[(size_t)J * N + i0 + tid] = s;
  } else if (I != J) {                   // rows of J (cols) -> slot I
    const int c = tid - 128;
    float m = CM[c], s = CS[c];
    mergeMS(m, s, CM[128 + c], CS[128 + c]);
    m_part[(size_t)I * N + j0 + c] = m;
    s_part[(size_t)I * N + j0 + c] = s;
  }
}

// ---- combine the 64 partials per row (4-way p-split), per-class sums ------
__global__ void combine_kernel(const float* __restrict__ m_part,
                               const float* __restrict__ s_part,
                               const int* __restrict__ labels,
                               float* __restrict__ classSum,
                               int* __restrict__ classCnt)
{
  __shared__ float MB[4][64], SB[4][64];
  const int jloc = threadIdx.x & 63;
  const int pc = threadIdx.x >> 6;        // 0..3
  const int j = blockIdx.x * 64 + jloc;
  float M = -1e20f, S = 0.f;
  for (int p = pc * 16; p < pc * 16 + 16; ++p)
    mergeMS(M, S, m_part[(size_t)p * N + j], s_part[(size_t)p * N + j]);
  MB[pc][jloc] = M; SB[pc][jloc] = S;
  __syncthreads();
  if (pc == 0) {
#pragma unroll
    for (int q = 1; q < 4; ++q) mergeMS(M, S, MB[q][jloc], SB[q][jloc]);
    int c = labels[j >> 1];
    atomicAdd(&classSum[c], S);
    atomicAdd(&classCnt[c], 1);
  }
}

// ---- finalize: loss = (1/N) * sum_c cnt_c * log(x_c + 1e-12) --------------
__global__ void final_kernel(const float* __restrict__ classSum,
                             const int* __restrict__ classCnt,
                             float* __restrict__ out)
{
  __shared__ float red[128];
  int t = threadIdx.x;
  float total = 0.f;
  for (int c = 0; c < NCLS; ++c) total += classSum[c];
  float term = 0.f;
  if (t < NCLS) {
    int cnt = classCnt[t];
    if (cnt > 0) {
      float x = (total - classSum[t]) / (float)(N - cnt) + 1e-12f;
      term = (float)cnt * logf(x);
    }
  }
  red[t] = term;
  __syncthreads();
  for (int s = 64; s > 0; s >>= 1) {
    if (t < s) red[t] += red[t + s];
    __syncthreads();
  }
  if (t == 0) out[0] = red[0] / (float)N;
}

extern "C" void kernel_launch(void* const* d_in, const int* in_sizes, int n_in,
                              void* d_out, int out_size, void* d_ws, size_t ws_size,
                              hipStream_t stream)
{
  (void)in_sizes; (void)n_in; (void)out_size; (void)ws_size;
  const float* F = (const float*)d_in[0];
  const int* labels = (const int*)d_in[1];
  float* out = (float*)d_out;

  // ws: Ahi (8MB) | Alo (8MB) | m_part (2MB) | s_part (2MB) | class arrays
  char* ws = (char*)d_ws;
  u16* Ahi = (u16*)ws;
  u16* Alo = (u16*)(ws + (size_t)N * DIM * 2);
  float* m_part = (float*)(ws + (size_t)N * DIM * 4);
  float* s_part = m_part + (size_t)NPART * N;
  float* classSum = s_part + (size_t)NPART * N;
  int* classCnt = (int*)(classSum + NCLS);

  prep_kernel<<<(N * DIM) / 1024, 256, 0, stream>>>(F, Ahi, Alo, classSum, classCnt);
  gram_flash<<<NTILE, 256, 0, stream>>>(Ahi, Alo, labels, m_part, s_part);
  combine_kernel<<<N / 64, 256, 0, stream>>>(m_part, s_part, labels, classSum, classCnt);
  final_kernel<<<1, 128, 0, stream>>>(classSum, classCnt, out);
}